// Round 1
// 667.047 us; speedup vs baseline: 1.0651x; 1.0651x over previous
//
#include <hip/hip_runtime.h>

#define B_ROWS   131072
#define MTILE    32
#define KCHUNKS  17        // 544 / 32
#define LDA      552       // At leading dim in f16: 544 + 8 pad (row stride 1104B = 20 dwords mod 32 -> 2-way, free)
// ws layout: [0, 512KB) mask u32; [512KB, +557056) W1t fp16 [512][544]
#define W1T_OFF  ((size_t)B_ROWS * 4)

typedef _Float16 f16x8 __attribute__((ext_vector_type(8)));
typedef float    f32x4 __attribute__((ext_vector_type(4)));

__device__ inline unsigned short f2h(float f) {
  _Float16 h = (_Float16)f;
  return __builtin_bit_cast(unsigned short, h);
}
__device__ inline float selu_f(float x) {
  const float lam = 1.0507009873554805f, alp = 1.6732632423543772f;
  return x > 0.f ? lam * x : lam * alp * (__expf(x) - 1.f);
}

__global__ void scatter_mask(const int* __restrict__ coords,
                             unsigned int* __restrict__ mask) {
  int i = blockIdx.x * 256 + threadIdx.x;
  mask[coords[i]] = 1u;
}

// W1 fp32 [526][512] -> W1t fp16 [n=512][k=544], K-permuted:
//   k<512: feature weights (orig row k+14); 512<=k<526: jnt rows (orig row k-512); else 0
__global__ void build_w1t(const float* __restrict__ W1,
                          unsigned short* __restrict__ W1t) {
  int n = blockIdx.x;      // 0..511
  int k = threadIdx.x;     // 0..543
  float v = 0.f;
  if (k < 512)       v = W1[(size_t)(k + 14) * 512 + n];
  else if (k < 526)  v = W1[(size_t)(k - 512) * 512 + n];
  W1t[(size_t)n * 544 + k] = f2h(v);
}

struct __align__(16) SMem {
  // union region: At[32][552] f16 = 35328B  (K loop, read-only after build)
  //               X2[32][520] f16 = 33280B  (epilogue)
  char buf[35328];
  float rsum[MTILE], rsq[MTILE], mean2[MTILE], rstd2[MTILE];
};

__global__ __launch_bounds__(256) void actor_main(
    const float* __restrict__ feat, const unsigned int* __restrict__ mask,
    const float* __restrict__ jp, const float* __restrict__ jg,
    const float* __restrict__ ln1g, const float* __restrict__ ln1b,
    const unsigned short* __restrict__ W1t, const float* __restrict__ b1,
    const float* __restrict__ ln2g, const float* __restrict__ ln2b,
    const float* __restrict__ W2, const float* __restrict__ b2,
    float* __restrict__ out) {
  __shared__ SMem sm;
  unsigned short* At = (unsigned short*)sm.buf;  // [32][LDA] f16
  unsigned short* X2 = (unsigned short*)sm.buf;  // [32][520] f16 (epilogue union)

  const int tid  = threadIdx.x;
  const int wave = tid >> 6;
  const int lane = tid & 63;
  const int m0   = blockIdx.x * MTILE;
  const int mrow = lane & 15;
  const int quad = lane >> 4;

  if (tid < MTILE) { sm.rsum[tid] = 0.f; sm.rsq[tid] = 0.f; }

  // ---------- A build: fused LN1 stats + SELU, full [32][544] f16 tile ----------
  // thread (arow=tid>>3, acg=tid&7): row m0+arow, cols {c*32 + acg*4 .. +4}.
  // Row held in 16 float4 regs -> feat read ONCE (phase-0 pass eliminated).
  {
    const int arow = tid >> 3;
    const int acg  = tid & 7;
    const int row  = m0 + arow;
    const float4* frow = (const float4*)feat + (size_t)row * 128 + acg;
    float4 f[16];
    float s = 0.f, q = 0.f;
#pragma unroll
    for (int c = 0; c < 16; ++c) {
      float4 v = frow[(size_t)c * 8];
      f[c] = v;
      s += v.x + v.y + v.z + v.w;
      q += v.x * v.x + v.y * v.y + v.z * v.z + v.w * v.w;
    }
    // 8 lanes (same arow) hold disjoint col partials; lanes arow*8..+7 are wave-contiguous
    s += __shfl_xor(s, 1); q += __shfl_xor(q, 1);
    s += __shfl_xor(s, 2); q += __shfl_xor(q, 2);
    s += __shfl_xor(s, 4); q += __shfl_xor(q, 4);
    float mk   = mask[row] ? 1.f : 0.f;  // masked-out row => y=0 => LN -> b -> selu(b)
    float mean = mk * s * (1.f / 512.f);
    float msq  = mk * q * (1.f / 512.f);
    float rstd = rsqrtf(msq - mean * mean + 1e-5f);
#pragma unroll
    for (int c = 0; c < 16; ++c) {
      float4 g = ((const float4*)ln1g)[c * 8 + acg];
      float4 b = ((const float4*)ln1b)[c * 8 + acg];
      union { unsigned short us[4]; uint2 u; } pk;
      pk.us[0] = f2h(selu_f((f[c].x * mk - mean) * rstd * g.x + b.x));
      pk.us[1] = f2h(selu_f((f[c].y * mk - mean) * rstd * g.y + b.y));
      pk.us[2] = f2h(selu_f((f[c].z * mk - mean) * rstd * g.z + b.z));
      pk.us[3] = f2h(selu_f((f[c].w * mk - mean) * rstd * g.w + b.w));
      *(uint2*)&At[arow * LDA + c * 32 + acg * 4] = pk.u;
    }
    {  // jnt chunk: cols 512..543  (jp[0..7), jg[7..14), zero pad [14..32))
      union { unsigned short us[4]; uint2 u; } pk;
#pragma unroll
      for (int q2 = 0; q2 < 4; ++q2) {
        int kk = acg * 4 + q2;
        float val = 0.f;
        if (kk < 7)       val = jp[(size_t)row * 7 + kk];
        else if (kk < 14) val = jg[(size_t)row * 7 + kk - 7];
        pk.us[q2] = f2h(val);
      }
      *(uint2*)&At[arow * LDA + 512 + acg * 4] = pk.u;
    }
  }
  __syncthreads();  // the ONLY barrier before the K loop

  // ---------- K loop: BARRIER-FREE ----------
  // A fragments from LDS (read-only). B fragments straight from global W1t
  // (557KB -> L2-resident per XCD) in exact MFMA fragment layout, register
  // ping-pong double buffered so chunk c+1 loads fly under chunk c MFMAs.
  f32x4 acc[2][8];
#pragma unroll
  for (int mi = 0; mi < 2; ++mi)
#pragma unroll
    for (int ni = 0; ni < 8; ++ni) acc[mi][ni] = (f32x4){0.f, 0.f, 0.f, 0.f};

  const unsigned short* wB = W1t + (size_t)(wave * 128 + mrow) * 544 + quad * 8;
  const unsigned short* aB = At + mrow * LDA + quad * 8;

  auto loadB = [&](f16x8* dst, int c) {
#pragma unroll
    for (int ni = 0; ni < 8; ++ni)
      dst[ni] = *(const f16x8*)(wB + (size_t)ni * (16 * 544) + c * 32);
  };
  auto step = [&](const f16x8* bF, int c) {
    f16x8 a0 = *(const f16x8*)(aB + c * 32);
    f16x8 a1 = *(const f16x8*)(aB + 16 * LDA + c * 32);
#pragma unroll
    for (int ni = 0; ni < 8; ++ni) {
      acc[0][ni] = __builtin_amdgcn_mfma_f32_16x16x32_f16(a0, bF[ni], acc[0][ni], 0, 0, 0);
      acc[1][ni] = __builtin_amdgcn_mfma_f32_16x16x32_f16(a1, bF[ni], acc[1][ni], 0, 0, 0);
    }
  };

  {
    f16x8 bEven[8], bOdd[8];
    loadB(bEven, 0);
    for (int c = 0; c < KCHUNKS - 1; c += 2) {  // c = 0,2,...,14
      loadB(bOdd, c + 1);
      step(bEven, c);
      loadB(bEven, c + 2);                      // c+2 <= 16, always valid
      step(bOdd, c + 1);
    }
    step(bEven, 16);
  }

  // ---------- epilogue: +b1, LN2 stats (cross-wave via LDS atomics) ----------
  float b1v[8], g2v[8], bl2v[8];
#pragma unroll
  for (int ni = 0; ni < 8; ++ni) {
    int col = wave * 128 + ni * 16 + mrow;
    b1v[ni] = b1[col]; g2v[ni] = ln2g[col]; bl2v[ni] = ln2b[col];
  }
#pragma unroll
  for (int mi = 0; mi < 2; ++mi)
#pragma unroll
    for (int reg = 0; reg < 4; ++reg) {
      int r = mi * 16 + quad * 4 + reg;  // C/D layout: col=lane&15, row=quad*4+reg
      float s = 0.f, q = 0.f;
#pragma unroll
      for (int ni = 0; ni < 8; ++ni) {
        float v = acc[mi][ni][reg] + b1v[ni];
        acc[mi][ni][reg] = v;
        s += v; q += v * v;
      }
      s += __shfl_xor(s, 1); q += __shfl_xor(q, 1);
      s += __shfl_xor(s, 2); q += __shfl_xor(q, 2);
      s += __shfl_xor(s, 4); q += __shfl_xor(q, 4);
      s += __shfl_xor(s, 8); q += __shfl_xor(q, 8);
      if ((lane & 15) == 0) { atomicAdd(&sm.rsum[r], s); atomicAdd(&sm.rsq[r], q); }
    }
  __syncthreads();  // also guarantees all K-loop At reads are done before X2 overwrite
  if (tid < MTILE) {
    float mean = sm.rsum[tid] * (1.f / 512.f);
    float var  = sm.rsq[tid] * (1.f / 512.f) - mean * mean;
    sm.mean2[tid] = mean;
    sm.rstd2[tid] = rsqrtf(var + 1e-5f);
  }
  __syncthreads();
#pragma unroll
  for (int mi = 0; mi < 2; ++mi)
#pragma unroll
    for (int ni = 0; ni < 8; ++ni)
#pragma unroll
      for (int reg = 0; reg < 4; ++reg) {
        int r = mi * 16 + quad * 4 + reg;
        int col = wave * 128 + ni * 16 + mrow;
        float v = (acc[mi][ni][reg] - sm.mean2[r]) * sm.rstd2[r] * g2v[ni] + bl2v[ni];
        X2[r * 520 + col] = f2h(selu_f(v));
      }
  __syncthreads();

  // ---------- GEMM2 (512->7) + tanh, W2 register-resident ----------
  float w2r[56];  // lane covers k = lane*8..+8, all 7 outputs
  {
    const float4* wp = (const float4*)W2 + lane * 14;
#pragma unroll
    for (int i = 0; i < 14; ++i) {
      float4 t = wp[i];
      w2r[i * 4 + 0] = t.x; w2r[i * 4 + 1] = t.y;
      w2r[i * 4 + 2] = t.z; w2r[i * 4 + 3] = t.w;
    }
  }
  float b2v = (lane < 7) ? b2[lane] : 0.f;
  for (int i = 0; i < 8; ++i) {
    int r = wave * 8 + i;
    f16x8 xv = *(const f16x8*)&X2[r * 520 + lane * 8];
    float o0 = 0, o1 = 0, o2 = 0, o3 = 0, o4 = 0, o5 = 0, o6 = 0;
#pragma unroll
    for (int e = 0; e < 8; ++e) {
      float xf = (float)xv[e];
      o0 += xf * w2r[e * 7 + 0]; o1 += xf * w2r[e * 7 + 1];
      o2 += xf * w2r[e * 7 + 2]; o3 += xf * w2r[e * 7 + 3];
      o4 += xf * w2r[e * 7 + 4]; o5 += xf * w2r[e * 7 + 5];
      o6 += xf * w2r[e * 7 + 6];
    }
#pragma unroll
    for (int d = 32; d > 0; d >>= 1) {
      o0 += __shfl_xor(o0, d); o1 += __shfl_xor(o1, d); o2 += __shfl_xor(o2, d);
      o3 += __shfl_xor(o3, d); o4 += __shfl_xor(o4, d); o5 += __shfl_xor(o5, d);
      o6 += __shfl_xor(o6, d);
    }
    if (lane < 7) {
      float ov = o0;
      if (lane == 1) ov = o1; else if (lane == 2) ov = o2;
      else if (lane == 3) ov = o3; else if (lane == 4) ov = o4;
      else if (lane == 5) ov = o5; else if (lane == 6) ov = o6;
      out[(size_t)(m0 + r) * 7 + lane] = tanhf(ov + b2v);
    }
  }
}

extern "C" void kernel_launch(void* const* d_in, const int* in_sizes, int n_in,
                              void* d_out, int out_size, void* d_ws, size_t ws_size,
                              hipStream_t stream) {
  const float* feat  = (const float*)d_in[0];
  const int*   crd   = (const int*)d_in[1];
  const float* jp    = (const float*)d_in[2];
  const float* jg    = (const float*)d_in[3];
  const float* ln1g  = (const float*)d_in[4];
  const float* ln1b  = (const float*)d_in[5];
  const float* W1    = (const float*)d_in[6];
  const float* b1    = (const float*)d_in[7];
  const float* ln2g  = (const float*)d_in[8];
  const float* ln2b  = (const float*)d_in[9];
  const float* W2    = (const float*)d_in[10];
  const float* b2    = (const float*)d_in[11];
  float* out = (float*)d_out;

  unsigned int*   mask = (unsigned int*)d_ws;
  unsigned short* W1t  = (unsigned short*)((char*)d_ws + W1T_OFF);

  hipMemsetAsync(mask, 0, (size_t)B_ROWS * 4, stream);
  scatter_mask<<<B_ROWS / 256, 256, 0, stream>>>(crd, mask);
  build_w1t<<<512, 544, 0, stream>>>(W1, W1t);
  actor_main<<<B_ROWS / MTILE, 256, 0, stream>>>(
      feat, mask, jp, jg, ln1g, ln1b, W1t, b1, ln2g, ln2b, W2, b2, out);
}

// Round 3
// 520.689 us; speedup vs baseline: 1.3645x; 1.2811x over previous
//
#include <hip/hip_runtime.h>

#define B_ROWS   131072
#define MTILE    64
#define KCHUNKS  17        // 544 / 32
#define LDA      552       // At leading dim f16: 544+8 pad; row stride 1104B (16B-aligned, 2-way banks)
// ws layout: [0, 512KB) mask u32; [512KB, +557056) W1f fp16 pre-fragmented [544 frags][512]
#define W1T_OFF  ((size_t)B_ROWS * 4)

typedef _Float16 f16x8 __attribute__((ext_vector_type(8)));
typedef float    f32x4 __attribute__((ext_vector_type(4)));

__device__ inline unsigned short f2h(float f) {
  _Float16 h = (_Float16)f;
  return __builtin_bit_cast(unsigned short, h);
}
__device__ inline float selu_f(float x) {
  const float lam = 1.0507009873554805f, alp = 1.6732632423543772f;
  return x > 0.f ? lam * x : lam * alp * (__expf(x) - 1.f);
}

__global__ void scatter_mask(const int* __restrict__ coords,
                             unsigned int* __restrict__ mask) {
  int i = blockIdx.x * 256 + threadIdx.x;
  mask[coords[i]] = 1u;
}

// W1 fp32 [526][512] -> W1f fp16, PRE-FRAGMENTED in per-wave MFMA load order:
//   frag = (wq*17 + c)*4 + ni   (wq=N-slice wave 0..7, c=K-chunk 0..16, ni=0..3)
//   W1f[frag*512 + lane*8 + e] = W1t[n = wq*64+ni*16+(lane&15)][k = c*32+(lane>>4)*8+e]
// K-permutation: k<512 -> orig row k+14; 512<=k<526 -> jnt rows k-512; else 0.
__global__ void build_w1f(const float* __restrict__ W1,
                          unsigned short* __restrict__ W1f) {
  int fragIdx = blockIdx.x;           // 0..543
  int tid  = threadIdx.x;             // 0..511 = lane*8 + e
  int ni   = fragIdx & 3;
  int c    = (fragIdx >> 2) % 17;
  int wq   = fragIdx / 68;
  int lane = tid >> 3, e = tid & 7;
  int n = wq * 64 + ni * 16 + (lane & 15);
  int k = c * 32 + (lane >> 4) * 8 + e;
  float v = 0.f;
  if (k < 512)       v = W1[(size_t)(k + 14) * 512 + n];
  else if (k < 526)  v = W1[(size_t)(k - 512) * 512 + n];
  W1f[(size_t)fragIdx * 512 + tid] = f2h(v);
}

struct __align__(16) SMem {
  // union: At[64][552] f16 = 70656B (K loop)  /  X2[64][520] f16 = 66560B (epilogue)
  char buf[70656];
  float rsum[MTILE], rsq[MTILE], mean2[MTILE], rstd2[MTILE];
};

__global__ __launch_bounds__(512, 4) void actor_main(
    const float* __restrict__ feat, const unsigned int* __restrict__ mask,
    const float* __restrict__ jp, const float* __restrict__ jg,
    const float* __restrict__ ln1g, const float* __restrict__ ln1b,
    const unsigned short* __restrict__ W1f, const float* __restrict__ b1,
    const float* __restrict__ ln2g, const float* __restrict__ ln2b,
    const float* __restrict__ W2, const float* __restrict__ b2,
    float* __restrict__ out) {
  __shared__ SMem sm;
  unsigned short* At = (unsigned short*)sm.buf;  // [64][LDA] f16
  unsigned short* X2 = (unsigned short*)sm.buf;  // [64][520] f16 (epilogue union)

  const int tid  = threadIdx.x;
  const int wq   = tid >> 6;   // wave 0..7 = N-slice (64 cols each)
  const int lane = tid & 63;
  const int m0   = blockIdx.x * MTILE;
  const int mrow = lane & 15;
  const int quad = lane >> 4;

  if (tid < MTILE) { sm.rsum[tid] = 0.f; sm.rsq[tid] = 0.f; }

  // ---------- A build: fused LN1 stats + SELU, [64][544] f16 tile ----------
  // thread (arow=tid>>3 in 0..63, acg=tid&7): row m0+arow, cols {c*32+acg*4..+4}
  {
    const int arow = tid >> 3;
    const int acg  = tid & 7;
    const int row  = m0 + arow;
    const float4* frow = (const float4*)feat + (size_t)row * 128 + acg;
    float4 f[16];
    float s = 0.f, q = 0.f;
#pragma unroll
    for (int c = 0; c < 16; ++c) {
      float4 v = frow[(size_t)c * 8];
      f[c] = v;
      s += v.x + v.y + v.z + v.w;
      q += v.x * v.x + v.y * v.y + v.z * v.z + v.w * v.w;
    }
    // 8 threads (same arow) = consecutive lanes; reduce over acg
    s += __shfl_xor(s, 1); q += __shfl_xor(q, 1);
    s += __shfl_xor(s, 2); q += __shfl_xor(q, 2);
    s += __shfl_xor(s, 4); q += __shfl_xor(q, 4);
    float mk   = mask[row] ? 1.f : 0.f;  // masked-out row => y=0 => LN -> b -> selu(b)
    float mean = mk * s * (1.f / 512.f);
    float msq  = mk * q * (1.f / 512.f);
    float rstd = rsqrtf(msq - mean * mean + 1e-5f);
#pragma unroll
    for (int c = 0; c < 16; ++c) {
      float4 g = ((const float4*)ln1g)[c * 8 + acg];
      float4 b = ((const float4*)ln1b)[c * 8 + acg];
      union { unsigned short us[4]; uint2 u; } pk;
      pk.us[0] = f2h(selu_f((f[c].x * mk - mean) * rstd * g.x + b.x));
      pk.us[1] = f2h(selu_f((f[c].y * mk - mean) * rstd * g.y + b.y));
      pk.us[2] = f2h(selu_f((f[c].z * mk - mean) * rstd * g.z + b.z));
      pk.us[3] = f2h(selu_f((f[c].w * mk - mean) * rstd * g.w + b.w));
      *(uint2*)&At[arow * LDA + c * 32 + acg * 4] = pk.u;
    }
    {  // jnt chunk: cols 512..543 (jp[0..7), jg[7..14), zero pad)
      union { unsigned short us[4]; uint2 u; } pk;
#pragma unroll
      for (int q2 = 0; q2 < 4; ++q2) {
        int kk = acg * 4 + q2;
        float val = 0.f;
        if (kk < 7)       val = jp[(size_t)row * 7 + kk];
        else if (kk < 14) val = jg[(size_t)row * 7 + kk - 7];
        pk.us[q2] = f2h(val);
      }
      *(uint2*)&At[arow * LDA + 512 + acg * 4] = pk.u;
    }
  }
  __syncthreads();  // only barrier before K loop

  // ---------- K loop: barrier-free, coalesced pre-fragmented B, reg ping-pong ----------
  f32x4 acc[4][4];
#pragma unroll
  for (int mi = 0; mi < 4; ++mi)
#pragma unroll
    for (int ni = 0; ni < 4; ++ni) acc[mi][ni] = (f32x4){0.f, 0.f, 0.f, 0.f};

  const unsigned short* wBase = W1f + (size_t)wq * 68 * 512 + lane * 8;
  const unsigned short* aB = At + mrow * LDA + quad * 8;

  auto loadB = [&](f16x8* dst, int c) {
#pragma unroll
    for (int ni = 0; ni < 4; ++ni)
      dst[ni] = *(const f16x8*)(wBase + (size_t)(c * 4 + ni) * 512);
  };
  auto step = [&](const f16x8* bF, int c) {
    f16x8 a[4];
#pragma unroll
    for (int mi = 0; mi < 4; ++mi)
      a[mi] = *(const f16x8*)(aB + mi * 16 * LDA + c * 32);
#pragma unroll
    for (int mi = 0; mi < 4; ++mi)
#pragma unroll
      for (int ni = 0; ni < 4; ++ni)
        acc[mi][ni] = __builtin_amdgcn_mfma_f32_16x16x32_f16(a[mi], bF[ni], acc[mi][ni], 0, 0, 0);
  };

  {
    f16x8 bE[4], bO[4];
    loadB(bE, 0);
    for (int c = 0; c < KCHUNKS - 1; c += 2) {  // c = 0,2,...,14
      loadB(bO, c + 1);
      step(bE, c);
      loadB(bE, c + 2);                         // c+2 <= 16, valid
      step(bO, c + 1);
    }
    step(bE, 16);
  }

  // ---------- epilogue: +b1, LN2 stats (cross-wave via LDS atomics) ----------
  float b1v[4], g2v[4], bl2v[4];
#pragma unroll
  for (int ni = 0; ni < 4; ++ni) {
    int col = wq * 64 + ni * 16 + mrow;
    b1v[ni] = b1[col]; g2v[ni] = ln2g[col]; bl2v[ni] = ln2b[col];
  }
#pragma unroll
  for (int mi = 0; mi < 4; ++mi)
#pragma unroll
    for (int reg = 0; reg < 4; ++reg) {
      int r = mi * 16 + quad * 4 + reg;  // C/D layout: col=lane&15, row=quad*4+reg
      float s = 0.f, q = 0.f;
#pragma unroll
      for (int ni = 0; ni < 4; ++ni) {
        float v = acc[mi][ni][reg] + b1v[ni];
        acc[mi][ni][reg] = v;
        s += v; q += v * v;
      }
      s += __shfl_xor(s, 1); q += __shfl_xor(q, 1);
      s += __shfl_xor(s, 2); q += __shfl_xor(q, 2);
      s += __shfl_xor(s, 4); q += __shfl_xor(q, 4);
      s += __shfl_xor(s, 8); q += __shfl_xor(q, 8);
      if ((lane & 15) == 0) { atomicAdd(&sm.rsum[r], s); atomicAdd(&sm.rsq[r], q); }
    }
  __syncthreads();  // also: all At reads done before X2 overwrite
  if (tid < MTILE) {
    float mean = sm.rsum[tid] * (1.f / 512.f);
    float var  = sm.rsq[tid] * (1.f / 512.f) - mean * mean;
    sm.mean2[tid] = mean;
    sm.rstd2[tid] = rsqrtf(var + 1e-5f);
  }
  __syncthreads();
#pragma unroll
  for (int mi = 0; mi < 4; ++mi)
#pragma unroll
    for (int ni = 0; ni < 4; ++ni)
#pragma unroll
      for (int reg = 0; reg < 4; ++reg) {
        int r = mi * 16 + quad * 4 + reg;
        int col = wq * 64 + ni * 16 + mrow;
        float v = (acc[mi][ni][reg] - sm.mean2[r]) * sm.rstd2[r] * g2v[ni] + bl2v[ni];
        X2[r * 520 + col] = f2h(selu_f(v));
      }
  __syncthreads();

  // ---------- GEMM2 (512->7) + tanh, W2 register-resident; wave handles 8 rows ----------
  float w2r[56];  // lane covers k = lane*8..+8, all 7 outputs
  {
    const float4* wp = (const float4*)W2 + lane * 14;
#pragma unroll
    for (int i = 0; i < 14; ++i) {
      float4 t = wp[i];
      w2r[i * 4 + 0] = t.x; w2r[i * 4 + 1] = t.y;
      w2r[i * 4 + 2] = t.z; w2r[i * 4 + 3] = t.w;
    }
  }
  float b2v = (lane < 7) ? b2[lane] : 0.f;
  for (int i = 0; i < 8; ++i) {
    int r = wq * 8 + i;
    f16x8 xv = *(const f16x8*)&X2[r * 520 + lane * 8];
    float o0 = 0, o1 = 0, o2 = 0, o3 = 0, o4 = 0, o5 = 0, o6 = 0;
#pragma unroll
    for (int e = 0; e < 8; ++e) {
      float xf = (float)xv[e];
      o0 += xf * w2r[e * 7 + 0]; o1 += xf * w2r[e * 7 + 1];
      o2 += xf * w2r[e * 7 + 2]; o3 += xf * w2r[e * 7 + 3];
      o4 += xf * w2r[e * 7 + 4]; o5 += xf * w2r[e * 7 + 5];
      o6 += xf * w2r[e * 7 + 6];
    }
#pragma unroll
    for (int d = 32; d > 0; d >>= 1) {
      o0 += __shfl_xor(o0, d); o1 += __shfl_xor(o1, d); o2 += __shfl_xor(o2, d);
      o3 += __shfl_xor(o3, d); o4 += __shfl_xor(o4, d); o5 += __shfl_xor(o5, d);
      o6 += __shfl_xor(o6, d);
    }
    if (lane < 7) {
      float ov = o0;
      if (lane == 1) ov = o1; else if (lane == 2) ov = o2;
      else if (lane == 3) ov = o3; else if (lane == 4) ov = o4;
      else if (lane == 5) ov = o5; else if (lane == 6) ov = o6;
      out[(size_t)(m0 + r) * 7 + lane] = tanhf(ov + b2v);
    }
  }
}

extern "C" void kernel_launch(void* const* d_in, const int* in_sizes, int n_in,
                              void* d_out, int out_size, void* d_ws, size_t ws_size,
                              hipStream_t stream) {
  const float* feat  = (const float*)d_in[0];
  const int*   crd   = (const int*)d_in[1];
  const float* jp    = (const float*)d_in[2];
  const float* jg    = (const float*)d_in[3];
  const float* ln1g  = (const float*)d_in[4];
  const float* ln1b  = (const float*)d_in[5];
  const float* W1    = (const float*)d_in[6];
  const float* b1    = (const float*)d_in[7];
  const float* ln2g  = (const float*)d_in[8];
  const float* ln2b  = (const float*)d_in[9];
  const float* W2    = (const float*)d_in[10];
  const float* b2    = (const float*)d_in[11];
  float* out = (float*)d_out;

  unsigned int*   mask = (unsigned int*)d_ws;
  unsigned short* W1f  = (unsigned short*)((char*)d_ws + W1T_OFF);

  hipMemsetAsync(mask, 0, (size_t)B_ROWS * 4, stream);
  scatter_mask<<<B_ROWS / 256, 256, 0, stream>>>(crd, mask);
  build_w1f<<<544, 512, 0, stream>>>(W1, W1f);
  actor_main<<<B_ROWS / MTILE, 512, 0, stream>>>(
      feat, mask, jp, jg, ln1g, ln1b, W1f, b1, ln2g, ln2b, W2, b2, out);
}

// Round 4
// 502.147 us; speedup vs baseline: 1.4149x; 1.0369x over previous
//
#include <hip/hip_runtime.h>

#define B_ROWS   131072
#define MTILE    64
#define KCHUNKS  17        // 544 / 32
#define LDA      552       // At leading dim f16: 544+8 pad
#define LDX      528       // X2 leading dim f16: 512+16 pad (row stride 1056B = 8 banks -> mild conflicts)
// ws layout: [0,128KB) mask u8; [128KB,+557056) W1f f16 [544 frags][512]; then W2f f16 [16][512]
#define W1F_OFF  ((size_t)B_ROWS)
#define W2F_OFF  (W1F_OFF + (size_t)544 * 512 * 2)

typedef _Float16 f16x8 __attribute__((ext_vector_type(8)));
typedef float    f32x4 __attribute__((ext_vector_type(4)));

__device__ inline unsigned short f2h(float f) {
  _Float16 h = (_Float16)f;
  return __builtin_bit_cast(unsigned short, h);
}
__device__ inline float selu_f(float x) {
  const float lam = 1.0507009873554805f, alp = 1.6732632423543772f;
  return x > 0.f ? lam * x : lam * alp * (__expf(x) - 1.f);
}

__global__ void scatter_mask(const int* __restrict__ coords,
                             unsigned char* __restrict__ mask) {
  int i = blockIdx.x * 256 + threadIdx.x;
  mask[coords[i]] = 1u;
}

// Blocks 0..543: W1 fp32 [526][512] -> W1f f16 pre-fragmented, per-wave MFMA order:
//   frag = (wq*17 + c)*4 + ni;  W1f[frag*512 + lane*8 + e] = W1[k-perm][n]
//   n = wq*64+ni*16+(lane&15), k = c*32+(lane>>4)*8+e
//   K-perm: k<512 -> orig row k+14; 512<=k<526 -> jnt rows k-512; else 0.
// Read side coalesced via 32x16 LDS transpose tile.
// Blocks 544..559: W2 fp32 [512][7] -> W2f f16 [16 kchunks][512 lane-elems], n padded to 16.
__global__ void build_wf(const float* __restrict__ W1, const float* __restrict__ W2,
                         unsigned short* __restrict__ W1f, unsigned short* __restrict__ W2f) {
  int tid = threadIdx.x;               // 0..511
  if (blockIdx.x < 544) {
    int fragIdx = blockIdx.x;
    int ni = fragIdx & 3;
    int c  = (fragIdx >> 2) % 17;
    int wq = fragIdx / 68;
    int nbase = wq * 64 + ni * 16;
    __shared__ float t[32][17];        // [k_local][n_local], +1 pad
    int kl = tid >> 4, nl = tid & 15;  // coalesced read: consecutive tid -> consecutive n
    int kg = c * 32 + kl;
    float v = 0.f;
    if (kg < 512)      v = W1[(size_t)(kg + 14) * 512 + nbase + nl];
    else if (kg < 526) v = W1[(size_t)(kg - 512) * 512 + nbase + nl];
    t[kl][nl] = v;
    __syncthreads();
    int lane = tid >> 3, e = tid & 7;
    int k2 = ((lane >> 4) & 3) * 8 + e;
    int n2 = lane & 15;
    W1f[(size_t)fragIdx * 512 + tid] = f2h(t[k2][n2]);
  } else {
    int c2 = blockIdx.x - 544;         // 0..15
    int lane = tid >> 3, e = tid & 7;
    int n = lane & 15, quad = (lane >> 4) & 3;
    int k = c2 * 32 + quad * 8 + e;
    float v = (n < 7) ? W2[(size_t)k * 7 + n] : 0.f;
    W2f[(size_t)c2 * 512 + tid] = f2h(v);
  }
}

struct __align__(16) SMem {
  // union: At[64][552] f16 = 70656B (K loop)
  //        X2[64][528] f16 = 67584B + O[64][8] f32 = 2048B -> 69632B (epilogue)
  char buf[70656];
  float rsum[MTILE], rsq[MTILE], mean2[MTILE], rstd2[MTILE];
};

__global__ __launch_bounds__(512, 4) void actor_main(
    const float* __restrict__ feat, const unsigned char* __restrict__ mask,
    const float* __restrict__ jp, const float* __restrict__ jg,
    const float* __restrict__ ln1g, const float* __restrict__ ln1b,
    const unsigned short* __restrict__ W1f, const float* __restrict__ b1,
    const float* __restrict__ ln2g, const float* __restrict__ ln2b,
    const unsigned short* __restrict__ W2f, const float* __restrict__ b2,
    float* __restrict__ out) {
  __shared__ SMem sm;
  unsigned short* At = (unsigned short*)sm.buf;            // [64][LDA] f16
  unsigned short* X2 = (unsigned short*)sm.buf;            // [64][LDX] f16 (epilogue union)
  float*          O  = (float*)(sm.buf + 64 * LDX * 2);    // [64][8] f32

  const int tid  = threadIdx.x;
  const int wq   = tid >> 6;   // wave 0..7 = N-slice (64 cols each)
  const int lane = tid & 63;
  const int m0   = blockIdx.x * MTILE;
  const int mrow = lane & 15;
  const int quad = lane >> 4;

  if (tid < MTILE) { sm.rsum[tid] = 0.f; sm.rsq[tid] = 0.f; }

  // ---------- B chunk-0 prefetch (no dependency on At) ----------
  const unsigned short* wBase = W1f + (size_t)wq * 68 * 512 + lane * 8;
  f16x8 bE[4], bO[4];
#pragma unroll
  for (int ni = 0; ni < 4; ++ni)
    bE[ni] = *(const f16x8*)(wBase + (size_t)ni * 512);

  // ---------- A build: fused LN1 stats + SELU, [64][544] f16 tile ----------
  {
    const int arow = tid >> 3;
    const int acg  = tid & 7;
    const int row  = m0 + arow;
    const float4* frow = (const float4*)feat + (size_t)row * 128 + acg;
    float4 f[16];
    float s = 0.f, q = 0.f;
#pragma unroll
    for (int c = 0; c < 16; ++c) {
      float4 v = frow[(size_t)c * 8];
      f[c] = v;
      s += v.x + v.y + v.z + v.w;
      q += v.x * v.x + v.y * v.y + v.z * v.z + v.w * v.w;
    }
    s += __shfl_xor(s, 1); q += __shfl_xor(q, 1);
    s += __shfl_xor(s, 2); q += __shfl_xor(q, 2);
    s += __shfl_xor(s, 4); q += __shfl_xor(q, 4);
    float mk   = mask[row] ? 1.f : 0.f;  // masked-out row => y=0 => LN -> b -> selu(b)
    float mean = mk * s * (1.f / 512.f);
    float msq  = mk * q * (1.f / 512.f);
    float rstd = rsqrtf(msq - mean * mean + 1e-5f);
#pragma unroll
    for (int c = 0; c < 16; ++c) {
      float4 g = ((const float4*)ln1g)[c * 8 + acg];
      float4 b = ((const float4*)ln1b)[c * 8 + acg];
      union { unsigned short us[4]; uint2 u; } pk;
      pk.us[0] = f2h(selu_f((f[c].x * mk - mean) * rstd * g.x + b.x));
      pk.us[1] = f2h(selu_f((f[c].y * mk - mean) * rstd * g.y + b.y));
      pk.us[2] = f2h(selu_f((f[c].z * mk - mean) * rstd * g.z + b.z));
      pk.us[3] = f2h(selu_f((f[c].w * mk - mean) * rstd * g.w + b.w));
      *(uint2*)&At[arow * LDA + c * 32 + acg * 4] = pk.u;
    }
    {  // jnt chunk: cols 512..543 (jp[0..7), jg[7..14), zero pad)
      union { unsigned short us[4]; uint2 u; } pk;
#pragma unroll
      for (int q2 = 0; q2 < 4; ++q2) {
        int kk = acg * 4 + q2;
        float val = 0.f;
        if (kk < 7)       val = jp[(size_t)row * 7 + kk];
        else if (kk < 14) val = jg[(size_t)row * 7 + kk - 7];
        pk.us[q2] = f2h(val);
      }
      *(uint2*)&At[arow * LDA + 512 + acg * 4] = pk.u;
    }
  }
  __syncthreads();  // barrier #1 (only one before K loop)

  // ---------- K loop: barrier-free, pre-fragmented B, reg ping-pong ----------
  f32x4 acc[4][4];
#pragma unroll
  for (int mi = 0; mi < 4; ++mi)
#pragma unroll
    for (int ni = 0; ni < 4; ++ni) acc[mi][ni] = (f32x4){0.f, 0.f, 0.f, 0.f};

  const unsigned short* aB = At + mrow * LDA + quad * 8;

  auto loadB = [&](f16x8* dst, int c) {
#pragma unroll
    for (int ni = 0; ni < 4; ++ni)
      dst[ni] = *(const f16x8*)(wBase + (size_t)(c * 4 + ni) * 512);
  };
  auto step = [&](const f16x8* bF, int c) {
    f16x8 a[4];
#pragma unroll
    for (int mi = 0; mi < 4; ++mi)
      a[mi] = *(const f16x8*)(aB + mi * 16 * LDA + c * 32);
#pragma unroll
    for (int mi = 0; mi < 4; ++mi)
#pragma unroll
      for (int ni = 0; ni < 4; ++ni)
        acc[mi][ni] = __builtin_amdgcn_mfma_f32_16x16x32_f16(a[mi], bF[ni], acc[mi][ni], 0, 0, 0);
  };

  for (int c = 0; c < KCHUNKS - 1; c += 2) {  // c = 0,2,...,14
    loadB(bO, c + 1);
    step(bE, c);
    loadB(bE, c + 2);                         // c+2 <= 16, valid
    step(bO, c + 1);
  }
  step(bE, 16);

  // ---------- GEMM2 B-frag prefetch (wave's own K-slice k = wq*64..+64) ----------
  f16x8 bW2[2];
  bW2[0] = *(const f16x8*)&W2f[(size_t)(2 * wq)     * 512 + lane * 8];
  bW2[1] = *(const f16x8*)&W2f[(size_t)(2 * wq + 1) * 512 + lane * 8];

  // ---------- epilogue: +b1, LN2 stats (cross-wave via LDS atomics) ----------
  float b1v[4], g2v[4], bl2v[4];
#pragma unroll
  for (int ni = 0; ni < 4; ++ni) {
    int col = wq * 64 + ni * 16 + mrow;
    b1v[ni] = b1[col]; g2v[ni] = ln2g[col]; bl2v[ni] = ln2b[col];
  }
#pragma unroll
  for (int mi = 0; mi < 4; ++mi)
#pragma unroll
    for (int reg = 0; reg < 4; ++reg) {
      int r = mi * 16 + quad * 4 + reg;  // C/D layout: col=lane&15, row=quad*4+reg
      float s = 0.f, q = 0.f;
#pragma unroll
      for (int ni = 0; ni < 4; ++ni) {
        float v = acc[mi][ni][reg] + b1v[ni];
        acc[mi][ni][reg] = v;
        s += v; q += v * v;
      }
      s += __shfl_xor(s, 1); q += __shfl_xor(q, 1);
      s += __shfl_xor(s, 2); q += __shfl_xor(q, 2);
      s += __shfl_xor(s, 4); q += __shfl_xor(q, 4);
      s += __shfl_xor(s, 8); q += __shfl_xor(q, 8);
      if ((lane & 15) == 0) { atomicAdd(&sm.rsum[r], s); atomicAdd(&sm.rsq[r], q); }
    }
  __syncthreads();  // barrier #2: K-loop At reads done; stats complete
  if (tid < MTILE) {
    float mean = sm.rsum[tid] * (1.f / 512.f);
    float var  = sm.rsq[tid] * (1.f / 512.f) - mean * mean;
    sm.mean2[tid] = mean;
    sm.rstd2[tid] = rsqrtf(var + 1e-5f);
  }
  O[tid] = 0.f;     // 64x8 = 512 floats, region beyond X2, At dead
  __syncthreads();  // barrier #3: mean2/rstd2 + O ready
#pragma unroll
  for (int mi = 0; mi < 4; ++mi)
#pragma unroll
    for (int ni = 0; ni < 4; ++ni)
#pragma unroll
      for (int reg = 0; reg < 4; ++reg) {
        int r = mi * 16 + quad * 4 + reg;
        int col = wq * 64 + ni * 16 + mrow;
        float v = (acc[mi][ni][reg] - sm.mean2[r]) * sm.rstd2[r] * g2v[ni] + bl2v[ni];
        X2[r * LDX + col] = f2h(selu_f(v));
      }
  __syncthreads();  // barrier #4: X2 complete

  // ---------- GEMM2 (512->7) via MFMA, K-split across waves, LDS f32 reduce ----------
  {
    f32x4 acc2[4];
#pragma unroll
    for (int mi = 0; mi < 4; ++mi) acc2[mi] = (f32x4){0.f, 0.f, 0.f, 0.f};
#pragma unroll
    for (int j = 0; j < 2; ++j) {
      int c2 = 2 * wq + j;
#pragma unroll
      for (int mi = 0; mi < 4; ++mi) {
        f16x8 a = *(const f16x8*)&X2[(mi * 16 + mrow) * LDX + c2 * 32 + quad * 8];
        acc2[mi] = __builtin_amdgcn_mfma_f32_16x16x32_f16(a, bW2[j], acc2[mi], 0, 0, 0);
      }
    }
#pragma unroll
    for (int mi = 0; mi < 4; ++mi)
#pragma unroll
      for (int reg = 0; reg < 4; ++reg)
        if (mrow < 7)
          atomicAdd(&O[(mi * 16 + quad * 4 + reg) * 8 + mrow], acc2[mi][reg]);
  }
  __syncthreads();  // barrier #5: O complete
  {
    int r = tid >> 3, c = tid & 7;
    if (c < 7)
      out[(size_t)(m0 + r) * 7 + c] = tanhf(O[tid] + b2[c]);
  }
}

extern "C" void kernel_launch(void* const* d_in, const int* in_sizes, int n_in,
                              void* d_out, int out_size, void* d_ws, size_t ws_size,
                              hipStream_t stream) {
  const float* feat  = (const float*)d_in[0];
  const int*   crd   = (const int*)d_in[1];
  const float* jp    = (const float*)d_in[2];
  const float* jg    = (const float*)d_in[3];
  const float* ln1g  = (const float*)d_in[4];
  const float* ln1b  = (const float*)d_in[5];
  const float* W1    = (const float*)d_in[6];
  const float* b1    = (const float*)d_in[7];
  const float* ln2g  = (const float*)d_in[8];
  const float* ln2b  = (const float*)d_in[9];
  const float* W2    = (const float*)d_in[10];
  const float* b2    = (const float*)d_in[11];
  float* out = (float*)d_out;

  unsigned char*  mask = (unsigned char*)d_ws;
  unsigned short* W1f  = (unsigned short*)((char*)d_ws + W1F_OFF);
  unsigned short* W2f  = (unsigned short*)((char*)d_ws + W2F_OFF);

  hipMemsetAsync(mask, 0, (size_t)B_ROWS, stream);
  scatter_mask<<<B_ROWS / 256, 256, 0, stream>>>(crd, mask);
  build_wf<<<560, 512, 0, stream>>>(W1, W2, W1f, W2f);
  actor_main<<<B_ROWS / MTILE, 512, 0, stream>>>(
      feat, mask, jp, jg, ln1g, ln1b, W1f, b1, ln2g, ln2b, W2f, b2, out);
}